// Round 17
// baseline (121.818 us; speedup 1.0000x reference)
//
#include <hip/hip_runtime.h>
#include <hip/hip_bf16.h>

// ---------------------------------------------------------------------------
// LogicLayer inference (size=1024, prev=1024, batch=16384)
//   out[s,n] = w0[s] + wA[s]*a + wB[s]*b + wAB[s]*a*b,  a = pA@prev, b = pB@prev
// Round 17: r15 structure with mfma_f32_32x32x16_bf16 (2382-2495 TF ubench
// vs 2075-2176 for 16x16x32 — ~17% faster MFMA pipe, half the instructions,
// identical operand bytes/ds_read count/staging/swizzle). Schedule family
// closed after 8 serial-sum results; this shrinks the MFMA summand instead.
//   - frags: per-wave 4(m)x2(n) 32x32 tiles, acc f32x16 x8 (same 128 AGPR)
//   - A/B frag: lane row=lane&31, k=(lane>>5)*8+0..7 (16B contiguous read)
//   - C/D: col=lane&31, row=(reg&3)+8*(reg>>2)+4*(lane>>5)  [m74/m101]
// ---------------------------------------------------------------------------

typedef __attribute__((ext_vector_type(8)))  short bf16x8;
typedef __attribute__((ext_vector_type(4)))  float f32x4;
typedef __attribute__((ext_vector_type(16))) float f32x16;

__device__ __forceinline__ void gload_lds16(const void* g, void* l) {
    __builtin_amdgcn_global_load_lds(
        (const __attribute__((address_space(1))) void*)g,
        (__attribute__((address_space(3))) void*)l, 16, 0, 0);
}

// ---------------- kernel 1: fused prep (transpose | softmax | coef) ---------
constexpr int Kp = 1024;     // prev_size
constexpr int Np = 16384;    // batch
constexpr int NTB = (Np / 64) * (Kp / 64);   // 4096 transpose blocks

__global__ __launch_bounds__(256) void prep_fused(
    const float* __restrict__ prev, __hip_bfloat16* __restrict__ prevT,
    const float* __restrict__ WA, const float* __restrict__ WB,
    __hip_bfloat16* __restrict__ PA, __hip_bfloat16* __restrict__ PB,
    const float* __restrict__ TW, float4* __restrict__ coef)
{
    const int bid = blockIdx.x;
    const int t = threadIdx.x;

    if (bid < NTB) {
        __shared__ float ls[64][65];
        const int n0 = (bid & 255) * 64;
        const int k0 = (bid >> 8) * 64;
        {
            const int kr = t >> 4, nc = (t & 15) * 4;
            #pragma unroll
            for (int i = 0; i < 4; ++i) {
                const int k = i * 16 + kr;
                float4 v = *(const float4*)&prev[(size_t)(k0 + k) * Np + n0 + nc];
                ls[k][nc + 0] = v.x; ls[k][nc + 1] = v.y;
                ls[k][nc + 2] = v.z; ls[k][nc + 3] = v.w;
            }
        }
        __syncthreads();
        {
            const int n = t >> 2, kc = (t & 3) * 16;
            __align__(16) __hip_bfloat16 tmp[16];
            #pragma unroll
            for (int j = 0; j < 16; ++j) tmp[j] = __float2bfloat16(ls[kc + j][n]);
            __hip_bfloat16* dst = &prevT[(size_t)(n0 + n) * Kp + k0 + kc];
            *(uint4*)(dst + 0) = *(const uint4*)&tmp[0];
            *(uint4*)(dst + 8) = *(const uint4*)&tmp[8];
        }
        return;
    }

    if (bid < NTB + 2048) {
        const int b = bid - NTB;
        const float* W;
        __hip_bfloat16* P;
        if (b < 1024) { W = WA + (size_t)b * Kp;          P = PA + (size_t)b * Kp; }
        else          { W = WB + (size_t)(b - 1024) * Kp; P = PB + (size_t)(b - 1024) * Kp; }

        const int wave = t >> 6, lane = t & 63;
        float4 v = *(const float4*)&W[t * 4];
        float mx = fmaxf(fmaxf(v.x, v.y), fmaxf(v.z, v.w));
        #pragma unroll
        for (int off = 32; off; off >>= 1) mx = fmaxf(mx, __shfl_xor(mx, off));

        __shared__ float redmax[4];
        __shared__ float redsum[4];
        if (lane == 0) redmax[wave] = mx;
        __syncthreads();
        mx = fmaxf(fmaxf(redmax[0], redmax[1]), fmaxf(redmax[2], redmax[3]));

        float e0 = __expf(v.x - mx), e1 = __expf(v.y - mx);
        float e2 = __expf(v.z - mx), e3 = __expf(v.w - mx);
        float s = e0 + e1 + e2 + e3;
        #pragma unroll
        for (int off = 32; off; off >>= 1) s += __shfl_xor(s, off);
        if (lane == 0) redsum[wave] = s;
        __syncthreads();
        s = redsum[0] + redsum[1] + redsum[2] + redsum[3];

        const float inv = 1.0f / s;
        __align__(8) __hip_bfloat16 o[4];
        o[0] = __float2bfloat16(e0 * inv);
        o[1] = __float2bfloat16(e1 * inv);
        o[2] = __float2bfloat16(e2 * inv);
        o[3] = __float2bfloat16(e3 * inv);
        *(uint2*)&P[t * 4] = *(const uint2*)o;
        return;
    }

    const int s = (bid - NTB - 2048) * 256 + t;
    if (s < 1024) {
        float p[16];
        float mx = -1e30f;
        #pragma unroll
        for (int g = 0; g < 16; ++g) { p[g] = TW[g * 1024 + s]; mx = fmaxf(mx, p[g]); }
        float sum = 0.f;
        #pragma unroll
        for (int g = 0; g < 16; ++g) { p[g] = __expf(p[g] - mx); sum += p[g]; }
        const float inv = 1.0f / sum;
        #pragma unroll
        for (int g = 0; g < 16; ++g) p[g] *= inv;
        float w0  = p[8] + p[9] + p[10] + p[11] + p[12] + p[13] + p[14] + p[15];
        float wA  = p[2] + p[3] + p[6] + p[7] - p[8] - p[9] - p[12] - p[13];
        float wB  = p[4] + p[5] + p[6] + p[7] - p[8] - p[9] - p[10] - p[11];
        float wAB = p[1] - p[2] - p[4] - 2.f * p[6] - p[7]
                  + p[8] + 2.f * p[9] + p[11] + p[13] - p[14];
        coef[s] = make_float4(w0, wA, wB, wAB);
    }
}

// ---------------- kernel 2: banked dual GEMM, 32x32x16 MFMA -----------------
// Block: 256 stacked A-rows (128 pA + 128 pB) x 256 cols, BK=64, 16 K-tiles.
// 8 waves 2(panel)x4(N); per-wave 128x64 out = acc[4][2] of 32x32 frags.
// LDS buffer 64KB: [ApA @0][ApB @16384][B @32768]; 2 buffers @0/65536.
// Row=128B, chunk-XOR swizzle identical to r4..r16 (staging unchanged).
constexpr int Kd = 1024;
constexpr int Nd = 16384;

__global__ __launch_bounds__(512, 2) void dual_gemm8(
    const __hip_bfloat16* __restrict__ pA,
    const __hip_bfloat16* __restrict__ pB,
    const __hip_bfloat16* __restrict__ prevT,
    const float4* __restrict__ coef,
    float* __restrict__ out)
{
    __shared__ __align__(16) char smem[131072];

    const int t_ = threadIdx.x;
    const int wave = t_ >> 6, lane = t_ & 63;
    const int wr = wave >> 2, wc = wave & 3;      // wr: 0=pA panel, 1=pB panel
    const int m0 = blockIdx.y * 128;
    const int n0 = blockIdx.x * 256;

    // fragment-read addressing (32x32x16: row = lane&31, k-half = lane>>5)
    const int rl  = lane & 31;
    const int kh  = lane >> 5;
    const int asw = rl & 7;
    // chunk byte for k-step ks (16 k = 2 chunks): ((ks*2+kh)^asw)*16
    const int ck0 = ((0 + kh) ^ asw) * 16;
    const int ck1 = ((2 + kh) ^ asw) * 16;
    const int ck2 = ((4 + kh) ^ asw) * 16;
    const int ck3 = ((6 + kh) ^ asw) * 16;
    const int cks[4] = {ck0, ck1, ck2, ck3};
    const int aoffs = (wr * 128 + rl) * 128;         // + fi*4096
    const int boffs = 32768 + (wc * 64 + rl) * 128;  // + fj*4096

    // staging addressing (pre-swizzled global source) — unchanged
    const int sr  = lane >> 3;
    const int swz = ((lane & 7) ^ sr) * 8;
    const int r0  = wave * 16 + sr;
    const __hip_bfloat16* gA0 = pA    + (size_t)(m0 + r0) * Kd + swz;
    const __hip_bfloat16* gA1 = pB    + (size_t)(m0 + r0) * Kd + swz;
    const __hip_bfloat16* gB0 = prevT + (size_t)(n0 + r0) * Kd + swz;
    const __hip_bfloat16* gB1 = prevT + (size_t)(n0 + 128 + r0) * Kd + swz;

    f32x16 acc[4][2] = {};                        // (fi, fj): 128 AGPR
    bf16x8 aL[8], aH[8], bL[4], bH[4];            // disjoint banks

#define STG(GP, BB, HOFF, KT) {                                             \
    char* lb = smem + (BB) + (HOFF) + wave * 2048;                          \
    gload_lds16((GP) + (KT), lb);                                           \
    gload_lds16((GP) + (KT) + 8 * Kd, lb + 1024); }

#define RD_AL(BB) _Pragma("unroll") for (int fi = 0; fi < 2; ++fi)          \
    _Pragma("unroll") for (int ks = 0; ks < 4; ++ks)                        \
        aL[fi*4+ks] = *(const bf16x8*)(smem + (BB) + aoffs + fi * 4096 + cks[ks]);
#define RD_AH(BB) _Pragma("unroll") for (int fi = 0; fi < 2; ++fi)          \
    _Pragma("unroll") for (int ks = 0; ks < 4; ++ks)                        \
        aH[fi*4+ks] = *(const bf16x8*)(smem + (BB) + aoffs + 8192 + fi * 4096 + cks[ks]);
#define RD_BL(BB) _Pragma("unroll") for (int ks = 0; ks < 4; ++ks)          \
        bL[ks] = *(const bf16x8*)(smem + (BB) + boffs + cks[ks]);
#define RD_BH(BB) _Pragma("unroll") for (int ks = 0; ks < 4; ++ks)          \
        bH[ks] = *(const bf16x8*)(smem + (BB) + boffs + 4096 + cks[ks]);

#define VMW(S) asm volatile("s_waitcnt " S ::: "memory")

// 8-MFMA quadrant (2 fi x 4 ks), with setprio (r13 A/B: helps ~4us).
#define MMQ(AB, BB, FI0, FJ)                                                \
    __builtin_amdgcn_s_setprio(1);                                          \
    _Pragma("unroll") for (int ks = 0; ks < 4; ++ks)                        \
    _Pragma("unroll") for (int fi = 0; fi < 2; ++fi)                        \
        acc[(FI0)+fi][FJ] = __builtin_amdgcn_mfma_f32_32x32x16_bf16(        \
            AB[fi*4+ks], BB[ks], acc[(FI0)+fi][FJ], 0, 0, 0);               \
    __builtin_amdgcn_s_setprio(0);

// One K-tile (r12/r15 calendar). Q1 stage gA(T+1), Q2 gB0(T+1), Q3 gB1(T+1);
// Q4-top vmcnt(0) drains loads aged 3/2/1 quadrants; ~300cy exposed. Full
// drain + barrier => NXT valid for tail reads. WAR as audited r12.
#define TILE(T, CURB, NXTB, SG, DOTAIL) {                                   \
    if (SG) { STG(gA0, NXTB, 0, ((T)+1)*64)                                 \
              STG(gA1, NXTB, 16384, ((T)+1)*64) }                           \
    RD_BH(CURB)                                                             \
    MMQ(aL, bL, 0, 0)                                                       \
    if (SG) { STG(gB0, NXTB, 32768, ((T)+1)*64) }                           \
    RD_AH(CURB)                                                             \
    MMQ(aL, bH, 0, 1)                                                       \
    if (SG) { STG(gB1, NXTB, 49152, ((T)+1)*64) }                           \
    MMQ(aH, bH, 2, 1)                                                       \
    VMW("vmcnt(0)");                                                        \
    __builtin_amdgcn_s_barrier();                                           \
    __builtin_amdgcn_sched_barrier(0);                                      \
    if (DOTAIL) { RD_AL(NXTB) }                                             \
    MMQ(aH, bL, 2, 0)                                                       \
    if (DOTAIL) { RD_BL(NXTB) }                                             \
}

    // prologue: stage tile0 -> buf0, drain, preload aL(0)/bL(0)
    STG(gA0, 0, 0,     0)
    STG(gA1, 0, 16384, 0)
    STG(gB0, 0, 32768, 0)
    STG(gB1, 0, 49152, 0)
    VMW("vmcnt(0)");
    __builtin_amdgcn_s_barrier();
    __builtin_amdgcn_sched_barrier(0);
    RD_AL(0) RD_BL(0)

    for (int t = 0; t < 15; ++t) {
        const int cb = (t & 1) << 16;
        TILE(t, cb, cb ^ 65536, 1, 1)
    }
    TILE(15, 65536, 0, 0, 0)

#undef TILE
#undef MMQ
#undef STG
#undef RD_AL
#undef RD_AH
#undef RD_BL
#undef RD_BH
#undef VMW

    // ---- epilogue: exchange b-acc via LDS, fuse bilinear coefficients ----
    // C/D map: col = lane&31, row = (reg&3) + 8*(reg>>2) + 4*(lane>>5).
    __syncthreads();
    if (wr == 1) {
        #pragma unroll
        for (int fi = 0; fi < 4; ++fi) {
            #pragma unroll
            for (int fj = 0; fj < 2; ++fj) {
                const int off = (((wc * 8 + fi * 2 + fj) * 64) + lane) * 64;
                *(f32x16*)(smem + off) = acc[fi][fj];
            }
        }
    }
    __syncthreads();
    if (wr == 0) {
        #pragma unroll
        for (int fi = 0; fi < 4; ++fi) {
            #pragma unroll
            for (int fj = 0; fj < 2; ++fj) {
                const f32x16 bb = *(const f32x16*)(smem +
                    (((wc * 8 + fi * 2 + fj) * 64) + lane) * 64);
                const int n = n0 + wc * 64 + fj * 32 + rl;
                #pragma unroll
                for (int r = 0; r < 16; ++r) {
                    const int m = m0 + fi * 32 + (r & 3) + 8 * (r >> 2) + 4 * kh;
                    const float4 c4 = coef[m];
                    const float aa = acc[fi][fj][r];
                    const float bv = bb[r];
                    out[(size_t)m * Nd + n] = c4.x + c4.y * aa + c4.z * bv
                                            + c4.w * (aa * bv);
                }
            }
        }
    }
}

// ---------------------------------------------------------------------------
extern "C" void kernel_launch(void* const* d_in, const int* in_sizes, int n_in,
                              void* d_out, int out_size, void* d_ws, size_t ws_size,
                              hipStream_t stream)
{
    const float* prev = (const float*)d_in[0];   // (prev_size, batch)
    const float* WA   = (const float*)d_in[1];   // (size, prev_size)
    const float* WB   = (const float*)d_in[2];   // (size, prev_size)
    const float* TW   = (const float*)d_in[3];   // (16, size)
    float* out = (float*)d_out;                  // (size, batch)

    const int size      = in_sizes[3] / 16;          // 1024
    const int prev_size = in_sizes[1] / size;        // 1024
    const int batch     = in_sizes[0] / prev_size;   // 16384

    char* ws = (char*)d_ws;
    __hip_bfloat16* prevT = (__hip_bfloat16*)ws;     // 32MB
    size_t off = (size_t)batch * prev_size * sizeof(__hip_bfloat16);
    __hip_bfloat16* pA = (__hip_bfloat16*)(ws + off);
    off += (size_t)size * prev_size * sizeof(__hip_bfloat16);
    __hip_bfloat16* pB = (__hip_bfloat16*)(ws + off);
    off += (size_t)size * prev_size * sizeof(__hip_bfloat16);
    float4* coef = (float4*)(ws + off);

    const int nprep = (batch / 64) * (prev_size / 64) + 2 * size + (size + 255) / 256;
    prep_fused<<<dim3(nprep), dim3(256), 0, stream>>>(
        prev, prevT, WA, WB, pA, pB, TW, coef);
    dual_gemm8<<<dim3(batch / 256, size / 128), dim3(512), 0, stream>>>(
        pA, pB, prevT, coef, out);
}

// Round 18
// 89.521 us; speedup vs baseline: 1.3608x; 1.3608x over previous
//
#include <hip/hip_runtime.h>
#include <hip/hip_bf16.h>

// ---------------------------------------------------------------------------
// LogicLayer inference (size=1024, prev=1024, batch=16384)
//   out[s,n] = w0[s] + wA[s]*a + wB[s]*b + wAB[s]*a*b,  a = pA@prev, b = pB@prev
// Round 18: 32x32x16 MFMA retained (layout correctness-verified in r17), with
// r17's two measured defects fixed:
//   1. K-sliced MFMA clusters: 8 MFMA/phase over all (fi,fj) = 8 independent
//      accumulator chains depth 1 (r17 had 2 chains x depth 4 -> pipe stall).
//      Operand banks E/O parity, read one phase ahead (r15 discipline).
//   2. Epilogue exchange in f32x4 quarters at 16B lane stride (r17's f32x16
//      64B-stride was a 16-way bank conflict: 8.65M cycles, arithmetic-matched).
//   Staging, swizzle, stage calendar, vmcnt(0)+barrier per tile: r15 verbatim.
// ---------------------------------------------------------------------------

typedef __attribute__((ext_vector_type(8)))  short bf16x8;
typedef __attribute__((ext_vector_type(4)))  float f32x4;
typedef __attribute__((ext_vector_type(16))) float f32x16;

__device__ __forceinline__ void gload_lds16(const void* g, void* l) {
    __builtin_amdgcn_global_load_lds(
        (const __attribute__((address_space(1))) void*)g,
        (__attribute__((address_space(3))) void*)l, 16, 0, 0);
}

// ---------------- kernel 1: fused prep (transpose | softmax | coef) ---------
constexpr int Kp = 1024;     // prev_size
constexpr int Np = 16384;    // batch
constexpr int NTB = (Np / 64) * (Kp / 64);   // 4096 transpose blocks

__global__ __launch_bounds__(256) void prep_fused(
    const float* __restrict__ prev, __hip_bfloat16* __restrict__ prevT,
    const float* __restrict__ WA, const float* __restrict__ WB,
    __hip_bfloat16* __restrict__ PA, __hip_bfloat16* __restrict__ PB,
    const float* __restrict__ TW, float4* __restrict__ coef)
{
    const int bid = blockIdx.x;
    const int t = threadIdx.x;

    if (bid < NTB) {
        __shared__ float ls[64][65];
        const int n0 = (bid & 255) * 64;
        const int k0 = (bid >> 8) * 64;
        {
            const int kr = t >> 4, nc = (t & 15) * 4;
            #pragma unroll
            for (int i = 0; i < 4; ++i) {
                const int k = i * 16 + kr;
                float4 v = *(const float4*)&prev[(size_t)(k0 + k) * Np + n0 + nc];
                ls[k][nc + 0] = v.x; ls[k][nc + 1] = v.y;
                ls[k][nc + 2] = v.z; ls[k][nc + 3] = v.w;
            }
        }
        __syncthreads();
        {
            const int n = t >> 2, kc = (t & 3) * 16;
            __align__(16) __hip_bfloat16 tmp[16];
            #pragma unroll
            for (int j = 0; j < 16; ++j) tmp[j] = __float2bfloat16(ls[kc + j][n]);
            __hip_bfloat16* dst = &prevT[(size_t)(n0 + n) * Kp + k0 + kc];
            *(uint4*)(dst + 0) = *(const uint4*)&tmp[0];
            *(uint4*)(dst + 8) = *(const uint4*)&tmp[8];
        }
        return;
    }

    if (bid < NTB + 2048) {
        const int b = bid - NTB;
        const float* W;
        __hip_bfloat16* P;
        if (b < 1024) { W = WA + (size_t)b * Kp;          P = PA + (size_t)b * Kp; }
        else          { W = WB + (size_t)(b - 1024) * Kp; P = PB + (size_t)(b - 1024) * Kp; }

        const int wave = t >> 6, lane = t & 63;
        float4 v = *(const float4*)&W[t * 4];
        float mx = fmaxf(fmaxf(v.x, v.y), fmaxf(v.z, v.w));
        #pragma unroll
        for (int off = 32; off; off >>= 1) mx = fmaxf(mx, __shfl_xor(mx, off));

        __shared__ float redmax[4];
        __shared__ float redsum[4];
        if (lane == 0) redmax[wave] = mx;
        __syncthreads();
        mx = fmaxf(fmaxf(redmax[0], redmax[1]), fmaxf(redmax[2], redmax[3]));

        float e0 = __expf(v.x - mx), e1 = __expf(v.y - mx);
        float e2 = __expf(v.z - mx), e3 = __expf(v.w - mx);
        float s = e0 + e1 + e2 + e3;
        #pragma unroll
        for (int off = 32; off; off >>= 1) s += __shfl_xor(s, off);
        if (lane == 0) redsum[wave] = s;
        __syncthreads();
        s = redsum[0] + redsum[1] + redsum[2] + redsum[3];

        const float inv = 1.0f / s;
        __align__(8) __hip_bfloat16 o[4];
        o[0] = __float2bfloat16(e0 * inv);
        o[1] = __float2bfloat16(e1 * inv);
        o[2] = __float2bfloat16(e2 * inv);
        o[3] = __float2bfloat16(e3 * inv);
        *(uint2*)&P[t * 4] = *(const uint2*)o;
        return;
    }

    const int s = (bid - NTB - 2048) * 256 + t;
    if (s < 1024) {
        float p[16];
        float mx = -1e30f;
        #pragma unroll
        for (int g = 0; g < 16; ++g) { p[g] = TW[g * 1024 + s]; mx = fmaxf(mx, p[g]); }
        float sum = 0.f;
        #pragma unroll
        for (int g = 0; g < 16; ++g) { p[g] = __expf(p[g] - mx); sum += p[g]; }
        const float inv = 1.0f / sum;
        #pragma unroll
        for (int g = 0; g < 16; ++g) p[g] *= inv;
        float w0  = p[8] + p[9] + p[10] + p[11] + p[12] + p[13] + p[14] + p[15];
        float wA  = p[2] + p[3] + p[6] + p[7] - p[8] - p[9] - p[12] - p[13];
        float wB  = p[4] + p[5] + p[6] + p[7] - p[8] - p[9] - p[10] - p[11];
        float wAB = p[1] - p[2] - p[4] - 2.f * p[6] - p[7]
                  + p[8] + 2.f * p[9] + p[11] + p[13] - p[14];
        coef[s] = make_float4(w0, wA, wB, wAB);
    }
}

// ---------------- kernel 2: dual GEMM, 32x32x16, K-sliced clusters ----------
// Block: 256 stacked A-rows (128 pA + 128 pB) x 256 cols, BK=64, 16 K-tiles.
// 8 waves 2(panel)x4(N); per-wave 128x64 out = acc[4][2] of 32x32 frags.
// LDS buffer 64KB: [ApA @0][ApB @16384][B @32768]; 2 buffers @0/65536.
// Row=128B, chunk-XOR swizzle (r4..r17 staging image, unchanged).
// Phase = one k-step ks: 8 MFMA over (fi,fj), banks E/O read 1 phase ahead.
constexpr int Kd = 1024;
constexpr int Nd = 16384;

__global__ __launch_bounds__(512, 2) void dual_gemm8(
    const __hip_bfloat16* __restrict__ pA,
    const __hip_bfloat16* __restrict__ pB,
    const __hip_bfloat16* __restrict__ prevT,
    const float4* __restrict__ coef,
    float* __restrict__ out)
{
    __shared__ __align__(16) char smem[131072];

    const int t_ = threadIdx.x;
    const int wave = t_ >> 6, lane = t_ & 63;
    const int wr = wave >> 2, wc = wave & 3;      // wr: 0=pA panel, 1=pB panel
    const int m0 = blockIdx.y * 128;
    const int n0 = blockIdx.x * 256;

    // fragment-read addressing (32x32x16: row = lane&31, k-half = lane>>5)
    const int rl  = lane & 31;
    const int kh  = lane >> 5;
    const int asw = rl & 7;
    const int cks[4] = { ((0 + kh) ^ asw) * 16, ((2 + kh) ^ asw) * 16,
                         ((4 + kh) ^ asw) * 16, ((6 + kh) ^ asw) * 16 };
    const int aoffs = (wr * 128 + rl) * 128;         // + fi*4096
    const int boffs = 32768 + (wc * 64 + rl) * 128;  // + fj*4096

    // staging addressing (pre-swizzled global source) — unchanged
    const int sr  = lane >> 3;
    const int swz = ((lane & 7) ^ sr) * 8;
    const int r0  = wave * 16 + sr;
    const __hip_bfloat16* gA0 = pA    + (size_t)(m0 + r0) * Kd + swz;
    const __hip_bfloat16* gA1 = pB    + (size_t)(m0 + r0) * Kd + swz;
    const __hip_bfloat16* gB0 = prevT + (size_t)(n0 + r0) * Kd + swz;
    const __hip_bfloat16* gB1 = prevT + (size_t)(n0 + 128 + r0) * Kd + swz;

    f32x16 acc[4][2] = {};                        // 128 AGPR
    bf16x8 aE[4], aO[4], bE[2], bO[2];            // E/O parity banks

#define STG(GP, BB, HOFF, KT) {                                             \
    char* lb = smem + (BB) + (HOFF) + wave * 2048;                          \
    gload_lds16((GP) + (KT), lb);                                           \
    gload_lds16((GP) + (KT) + 8 * Kd, lb + 1024); }

#define RD_A(BK, BB, KS) _Pragma("unroll") for (int fi = 0; fi < 4; ++fi)   \
    BK[fi] = *(const bf16x8*)(smem + (BB) + aoffs + fi * 4096 + cks[KS]);
#define RD_B(BK, BB, KS) _Pragma("unroll") for (int fj = 0; fj < 2; ++fj)   \
    BK[fj] = *(const bf16x8*)(smem + (BB) + boffs + fj * 4096 + cks[KS]);

#define VMW(S) asm volatile("s_waitcnt " S ::: "memory")

// 8-MFMA cluster: all (fi,fj) at one ks -> 8 independent chains, depth 1.
#define MMC(AB, BB)                                                         \
    __builtin_amdgcn_s_setprio(1);                                          \
    _Pragma("unroll") for (int fi = 0; fi < 4; ++fi)                        \
    _Pragma("unroll") for (int fj = 0; fj < 2; ++fj)                        \
        acc[fi][fj] = __builtin_amdgcn_mfma_f32_32x32x16_bf16(              \
            AB[fi], BB[fj], acc[fi][fj], 0, 0, 0);                          \
    __builtin_amdgcn_s_setprio(0);

// One K-tile (r15 calendar). ph0 stage gA(T+1), ph1 gB0(T+1), ph2 gB1(T+1);
// ph3-top vmcnt(0) drains loads aged 3/2/1 phases; full drain + barrier =>
// NXT valid for tail reads. ks parity: ks0/ks2 use E, ks1/ks3 use O; each
// ks's reads issued one phase (8 MFMA) before use.
#define TILE(T, CURB, NXTB, SG, DOTAIL) {                                   \
    if (SG) { STG(gA0, NXTB, 0, ((T)+1)*64)                                 \
              STG(gA1, NXTB, 16384, ((T)+1)*64) }                           \
    RD_A(aO, CURB, 1) RD_B(bO, CURB, 1)                                     \
    MMC(aE, bE)                                                             \
    if (SG) { STG(gB0, NXTB, 32768, ((T)+1)*64) }                           \
    RD_A(aE, CURB, 2) RD_B(bE, CURB, 2)                                     \
    MMC(aO, bO)                                                             \
    if (SG) { STG(gB1, NXTB, 49152, ((T)+1)*64) }                           \
    RD_A(aO, CURB, 3) RD_B(bO, CURB, 3)                                     \
    MMC(aE, bE)                                                             \
    VMW("vmcnt(0)");                                                        \
    __builtin_amdgcn_s_barrier();                                           \
    __builtin_amdgcn_sched_barrier(0);                                      \
    if (DOTAIL) { RD_A(aE, NXTB, 0) RD_B(bE, NXTB, 0) }                     \
    MMC(aO, bO)                                                             \
}

    // prologue: stage tile0 -> buf0, drain, preload ks0 banks
    STG(gA0, 0, 0,     0)
    STG(gA1, 0, 16384, 0)
    STG(gB0, 0, 32768, 0)
    STG(gB1, 0, 49152, 0)
    VMW("vmcnt(0)");
    __builtin_amdgcn_s_barrier();
    __builtin_amdgcn_sched_barrier(0);
    RD_A(aE, 0, 0) RD_B(bE, 0, 0)

    for (int t = 0; t < 15; ++t) {
        const int cb = (t & 1) << 16;
        TILE(t, cb, cb ^ 65536, 1, 1)
    }
    TILE(15, 65536, 0, 0, 0)

#undef TILE
#undef MMC
#undef STG
#undef RD_A
#undef RD_B
#undef VMW

    // ---- epilogue: exchange b-acc via LDS in f32x4 quarters (16B stride,
    // conflict-free — r17's 64B-stride f32x16 was the 8.65M-conflict bug) ----
    // C/D map: col = lane&31, row = (reg&3) + 8*(reg>>2) + 4*(lane>>5).
    __syncthreads();
    if (wr == 1) {
        #pragma unroll
        for (int fi = 0; fi < 4; ++fi) {
            #pragma unroll
            for (int fj = 0; fj < 2; ++fj) {
                const int frag = wc * 8 + fi * 2 + fj;
                #pragma unroll
                for (int q = 0; q < 4; ++q) {
                    f32x4 v = { acc[fi][fj][q*4+0], acc[fi][fj][q*4+1],
                                acc[fi][fj][q*4+2], acc[fi][fj][q*4+3] };
                    *(f32x4*)(smem + (((frag * 4 + q) * 64) + lane) * 16) = v;
                }
            }
        }
    }
    __syncthreads();
    if (wr == 0) {
        #pragma unroll
        for (int fi = 0; fi < 4; ++fi) {
            f32x4 bq[2][4];
            #pragma unroll
            for (int fj = 0; fj < 2; ++fj) {
                const int frag = wc * 8 + fi * 2 + fj;
                #pragma unroll
                for (int q = 0; q < 4; ++q)
                    bq[fj][q] = *(const f32x4*)(smem + (((frag * 4 + q) * 64) + lane) * 16);
            }
            #pragma unroll
            for (int r = 0; r < 16; ++r) {
                const int m = m0 + fi * 32 + (r & 3) + 8 * (r >> 2) + 4 * kh;
                const float4 c4 = coef[m];
                #pragma unroll
                for (int fj = 0; fj < 2; ++fj) {
                    const int n = n0 + wc * 64 + fj * 32 + rl;
                    const float aa = acc[fi][fj][r];
                    const float bv = bq[fj][r >> 2][r & 3];
                    out[(size_t)m * Nd + n] = c4.x + c4.y * aa + c4.z * bv
                                            + c4.w * (aa * bv);
                }
            }
        }
    }
}

// ---------------------------------------------------------------------------
extern "C" void kernel_launch(void* const* d_in, const int* in_sizes, int n_in,
                              void* d_out, int out_size, void* d_ws, size_t ws_size,
                              hipStream_t stream)
{
    const float* prev = (const float*)d_in[0];   // (prev_size, batch)
    const float* WA   = (const float*)d_in[1];   // (size, prev_size)
    const float* WB   = (const float*)d_in[2];   // (size, prev_size)
    const float* TW   = (const float*)d_in[3];   // (16, size)
    float* out = (float*)d_out;                  // (size, batch)

    const int size      = in_sizes[3] / 16;          // 1024
    const int prev_size = in_sizes[1] / size;        // 1024
    const int batch     = in_sizes[0] / prev_size;   // 16384

    char* ws = (char*)d_ws;
    __hip_bfloat16* prevT = (__hip_bfloat16*)ws;     // 32MB
    size_t off = (size_t)batch * prev_size * sizeof(__hip_bfloat16);
    __hip_bfloat16* pA = (__hip_bfloat16*)(ws + off);
    off += (size_t)size * prev_size * sizeof(__hip_bfloat16);
    __hip_bfloat16* pB = (__hip_bfloat16*)(ws + off);
    off += (size_t)size * prev_size * sizeof(__hip_bfloat16);
    float4* coef = (float4*)(ws + off);

    const int nprep = (batch / 64) * (prev_size / 64) + 2 * size + (size + 255) / 256;
    prep_fused<<<dim3(nprep), dim3(256), 0, stream>>>(
        prev, prevT, WA, WB, pA, pB, TW, coef);
    dual_gemm8<<<dim3(batch / 256, size / 128), dim3(512), 0, stream>>>(
        pA, pB, prevT, coef, out);
}

// Round 19
// 84.538 us; speedup vs baseline: 1.4410x; 1.0589x over previous
//
#include <hip/hip_runtime.h>
#include <hip/hip_bf16.h>

// ---------------------------------------------------------------------------
// LogicLayer inference (size=1024, prev=1024, batch=16384)
//   out[s,n] = w0[s] + wA[s]*a + wB[s]*b + wAB[s]*a*b,  a = pA@prev, b = pB@prev
// Round 19: REVERT to r15 (best measured: 84.5us total).
//   - prep_fused ~18.5us (~90% of the 108MB HBM floor)
//   - dual_gemm8 65.3us, MfmaUtil 42%, 0 bank conflicts (~92% of the
//     structure's serial-sum floor: MFMA 2483 + LDS 1536+512 + barrier cyc/tile)
// Closed by measurement: 8 schedule variants (serial-sum invariant),
// 128x128/wave (VGPR spill), 32x32x16 MFMA (inherent 6.29M read conflicts),
// transpose-into-GEMM fusion (negative). This is the family's ceiling.
// ---------------------------------------------------------------------------

typedef __attribute__((ext_vector_type(8))) short bf16x8;
typedef __attribute__((ext_vector_type(4))) float f32x4;

__device__ __forceinline__ void gload_lds16(const void* g, void* l) {
    __builtin_amdgcn_global_load_lds(
        (const __attribute__((address_space(1))) void*)g,
        (__attribute__((address_space(3))) void*)l, 16, 0, 0);
}

// ---------------- kernel 1: fused prep (transpose | softmax | coef) ---------
constexpr int Kp = 1024;     // prev_size
constexpr int Np = 16384;    // batch
constexpr int NTB = (Np / 64) * (Kp / 64);   // 4096 transpose blocks

__global__ __launch_bounds__(256) void prep_fused(
    const float* __restrict__ prev, __hip_bfloat16* __restrict__ prevT,
    const float* __restrict__ WA, const float* __restrict__ WB,
    __hip_bfloat16* __restrict__ PA, __hip_bfloat16* __restrict__ PB,
    const float* __restrict__ TW, float4* __restrict__ coef)
{
    const int bid = blockIdx.x;
    const int t = threadIdx.x;

    if (bid < NTB) {
        __shared__ float ls[64][65];
        const int n0 = (bid & 255) * 64;
        const int k0 = (bid >> 8) * 64;
        {
            const int kr = t >> 4, nc = (t & 15) * 4;
            #pragma unroll
            for (int i = 0; i < 4; ++i) {
                const int k = i * 16 + kr;
                float4 v = *(const float4*)&prev[(size_t)(k0 + k) * Np + n0 + nc];
                ls[k][nc + 0] = v.x; ls[k][nc + 1] = v.y;
                ls[k][nc + 2] = v.z; ls[k][nc + 3] = v.w;
            }
        }
        __syncthreads();
        {
            const int n = t >> 2, kc = (t & 3) * 16;
            __align__(16) __hip_bfloat16 tmp[16];
            #pragma unroll
            for (int j = 0; j < 16; ++j) tmp[j] = __float2bfloat16(ls[kc + j][n]);
            __hip_bfloat16* dst = &prevT[(size_t)(n0 + n) * Kp + k0 + kc];
            *(uint4*)(dst + 0) = *(const uint4*)&tmp[0];
            *(uint4*)(dst + 8) = *(const uint4*)&tmp[8];
        }
        return;
    }

    if (bid < NTB + 2048) {
        const int b = bid - NTB;
        const float* W;
        __hip_bfloat16* P;
        if (b < 1024) { W = WA + (size_t)b * Kp;          P = PA + (size_t)b * Kp; }
        else          { W = WB + (size_t)(b - 1024) * Kp; P = PB + (size_t)(b - 1024) * Kp; }

        const int wave = t >> 6, lane = t & 63;
        float4 v = *(const float4*)&W[t * 4];
        float mx = fmaxf(fmaxf(v.x, v.y), fmaxf(v.z, v.w));
        #pragma unroll
        for (int off = 32; off; off >>= 1) mx = fmaxf(mx, __shfl_xor(mx, off));

        __shared__ float redmax[4];
        __shared__ float redsum[4];
        if (lane == 0) redmax[wave] = mx;
        __syncthreads();
        mx = fmaxf(fmaxf(redmax[0], redmax[1]), fmaxf(redmax[2], redmax[3]));

        float e0 = __expf(v.x - mx), e1 = __expf(v.y - mx);
        float e2 = __expf(v.z - mx), e3 = __expf(v.w - mx);
        float s = e0 + e1 + e2 + e3;
        #pragma unroll
        for (int off = 32; off; off >>= 1) s += __shfl_xor(s, off);
        if (lane == 0) redsum[wave] = s;
        __syncthreads();
        s = redsum[0] + redsum[1] + redsum[2] + redsum[3];

        const float inv = 1.0f / s;
        __align__(8) __hip_bfloat16 o[4];
        o[0] = __float2bfloat16(e0 * inv);
        o[1] = __float2bfloat16(e1 * inv);
        o[2] = __float2bfloat16(e2 * inv);
        o[3] = __float2bfloat16(e3 * inv);
        *(uint2*)&P[t * 4] = *(const uint2*)o;
        return;
    }

    const int s = (bid - NTB - 2048) * 256 + t;
    if (s < 1024) {
        float p[16];
        float mx = -1e30f;
        #pragma unroll
        for (int g = 0; g < 16; ++g) { p[g] = TW[g * 1024 + s]; mx = fmaxf(mx, p[g]); }
        float sum = 0.f;
        #pragma unroll
        for (int g = 0; g < 16; ++g) { p[g] = __expf(p[g] - mx); sum += p[g]; }
        const float inv = 1.0f / sum;
        #pragma unroll
        for (int g = 0; g < 16; ++g) p[g] *= inv;
        float w0  = p[8] + p[9] + p[10] + p[11] + p[12] + p[13] + p[14] + p[15];
        float wA  = p[2] + p[3] + p[6] + p[7] - p[8] - p[9] - p[12] - p[13];
        float wB  = p[4] + p[5] + p[6] + p[7] - p[8] - p[9] - p[10] - p[11];
        float wAB = p[1] - p[2] - p[4] - 2.f * p[6] - p[7]
                  + p[8] + 2.f * p[9] + p[11] + p[13] - p[14];
        coef[s] = make_float4(w0, wA, wB, wAB);
    }
}

// ---------------- kernel 2: banked dual GEMM (r12/r15 verbatim) -------------
// Block: 256 stacked A-rows (128 pA + 128 pB) x 256 cols, BK=64, 16 K-tiles.
// 8 waves 2(panel)x4(N), per-wave 128x64 out = acc[8][4].
// LDS buffer 64KB: [ApA @0][ApB @16384][B n0-127 @32768][B n128-255 @49152];
// 2 buffers @0/65536. Row=128B, chunk-XOR swizzle.
// Banks: aL(i0-3) aH(i4-7) bL(j0-1) bH(j2-3), read 1 quadrant before use.
constexpr int Kd = 1024;
constexpr int Nd = 16384;

__global__ __launch_bounds__(512, 2) void dual_gemm8(
    const __hip_bfloat16* __restrict__ pA,
    const __hip_bfloat16* __restrict__ pB,
    const __hip_bfloat16* __restrict__ prevT,
    const float4* __restrict__ coef,
    float* __restrict__ out)
{
    __shared__ __align__(16) char smem[131072];

    const int t_ = threadIdx.x;
    const int wave = t_ >> 6, lane = t_ & 63;
    const int wr = wave >> 2, wc = wave & 3;      // wr: 0=pA panel, 1=pB panel
    const int m0 = blockIdx.y * 128;
    const int n0 = blockIdx.x * 256;

    // fragment-read addressing
    const int fr  = lane & 15;
    const int kg  = lane >> 4;
    const int fsw = fr & 7;
    const int c0 = (kg ^ fsw) * 16;               // kstep 0 chunk byte
    const int c1 = ((4 + kg) ^ fsw) * 16;         // kstep 1 chunk byte
    const int aoffs = (wr * 128 + fr) * 128;      // + i*2048 (+8192 for i4-7)
    const int boffs = 32768 + (wc * 64 + fr) * 128;  // + j*2048 (+4096 j2-3)

    // staging addressing (pre-swizzled global source)
    const int sr  = lane >> 3;
    const int swz = ((lane & 7) ^ sr) * 8;
    const int r0  = wave * 16 + sr;
    const __hip_bfloat16* gA0 = pA    + (size_t)(m0 + r0) * Kd + swz;
    const __hip_bfloat16* gA1 = pB    + (size_t)(m0 + r0) * Kd + swz;
    const __hip_bfloat16* gB0 = prevT + (size_t)(n0 + r0) * Kd + swz;
    const __hip_bfloat16* gB1 = prevT + (size_t)(n0 + 128 + r0) * Kd + swz;

    f32x4 acc[8][4] = {};
    bf16x8 aL[8], aH[8], bL[4], bH[4];            // disjoint banks

#define STG(GP, BB, HOFF, KT) {                                             \
    char* lb = smem + (BB) + (HOFF) + wave * 2048;                          \
    gload_lds16((GP) + (KT), lb);                                           \
    gload_lds16((GP) + (KT) + 8 * Kd, lb + 1024); }

#define RD_AL(BB) _Pragma("unroll") for (int i = 0; i < 4; ++i) {           \
    aL[i*2]   = *(const bf16x8*)(smem + (BB) + aoffs + i * 2048 + c0);      \
    aL[i*2+1] = *(const bf16x8*)(smem + (BB) + aoffs + i * 2048 + c1); }
#define RD_AH(BB) _Pragma("unroll") for (int i = 0; i < 4; ++i) {           \
    aH[i*2]   = *(const bf16x8*)(smem + (BB) + aoffs + 8192 + i * 2048 + c0); \
    aH[i*2+1] = *(const bf16x8*)(smem + (BB) + aoffs + 8192 + i * 2048 + c1); }
#define RD_BL(BB) _Pragma("unroll") for (int j = 0; j < 2; ++j) {           \
    bL[j*2]   = *(const bf16x8*)(smem + (BB) + boffs + j * 2048 + c0);      \
    bL[j*2+1] = *(const bf16x8*)(smem + (BB) + boffs + j * 2048 + c1); }
#define RD_BH(BB) _Pragma("unroll") for (int j = 0; j < 2; ++j) {           \
    bH[j*2]   = *(const bf16x8*)(smem + (BB) + boffs + 4096 + j * 2048 + c0); \
    bH[j*2+1] = *(const bf16x8*)(smem + (BB) + boffs + 4096 + j * 2048 + c1); }

#define VMW(S) asm volatile("s_waitcnt " S ::: "memory")

// 16-MFMA quadrant with setprio (r13 A/B: removing it cost ~4us).
#define MMQ(AB, BB, I0, J0)                                                 \
    __builtin_amdgcn_s_setprio(1);                                          \
    _Pragma("unroll") for (int i = 0; i < 4; ++i)                           \
    _Pragma("unroll") for (int j = 0; j < 2; ++j)                           \
    _Pragma("unroll") for (int ks = 0; ks < 2; ++ks)                        \
        acc[(I0)+i][(J0)+j] = __builtin_amdgcn_mfma_f32_16x16x32_bf16(      \
            AB[i*2+ks], BB[j*2+ks], acc[(I0)+i][(J0)+j], 0, 0, 0);          \
    __builtin_amdgcn_s_setprio(0);

// One K-tile. Stage calendar: Q1 gA(T+1)[4], Q2 gB0(T+1)[2], Q3 gB1(T+1)[2].
// Q4-top vmcnt(0) drains loads aged 3/2/1 quadrants (~1860/1240/620cy);
// ~300cy exposed. Full drain + barrier => NXT valid for tail reads.
#define TILE(T, CURB, NXTB, SG, DOTAIL) {                                   \
    if (SG) { STG(gA0, NXTB, 0, ((T)+1)*64)                                 \
              STG(gA1, NXTB, 16384, ((T)+1)*64) }                           \
    RD_BH(CURB)                                                             \
    MMQ(aL, bL, 0, 0)                                                       \
    if (SG) { STG(gB0, NXTB, 32768, ((T)+1)*64) }                           \
    RD_AH(CURB)                                                             \
    MMQ(aL, bH, 0, 2)                                                       \
    if (SG) { STG(gB1, NXTB, 49152, ((T)+1)*64) }                           \
    MMQ(aH, bH, 4, 2)                                                       \
    VMW("vmcnt(0)");                                                        \
    __builtin_amdgcn_s_barrier();                                           \
    __builtin_amdgcn_sched_barrier(0);                                      \
    if (DOTAIL) { RD_AL(NXTB) }                                             \
    MMQ(aH, bL, 4, 0)                                                       \
    if (DOTAIL) { RD_BL(NXTB) }                                             \
}

    // prologue: stage tile0 -> buf0, drain, preload aL(0)/bL(0)
    STG(gA0, 0, 0,     0)
    STG(gA1, 0, 16384, 0)
    STG(gB0, 0, 32768, 0)
    STG(gB1, 0, 49152, 0)
    VMW("vmcnt(0)");
    __builtin_amdgcn_s_barrier();
    __builtin_amdgcn_sched_barrier(0);
    RD_AL(0) RD_BL(0)

    for (int t = 0; t < 15; ++t) {
        const int cb = (t & 1) << 16;
        TILE(t, cb, cb ^ 65536, 1, 1)
    }
    TILE(15, 65536, 0, 0, 0)

#undef TILE
#undef MMQ
#undef STG
#undef RD_AL
#undef RD_AH
#undef RD_BL
#undef RD_BH
#undef VMW

    // ---- epilogue: exchange b-acc via LDS, fuse bilinear coefficients ----
    __syncthreads();
    if (wr == 1) {
        #pragma unroll
        for (int i = 0; i < 8; ++i) {
            #pragma unroll
            for (int j = 0; j < 4; ++j) {
                const int off = ((((wc * 8 + i) * 4 + j) * 64) + lane) * 16;
                *(f32x4*)(smem + off) = acc[i][j];
            }
        }
    }
    __syncthreads();
    if (wr == 0) {
        const int hi = lane >> 4;
        #pragma unroll
        for (int i = 0; i < 8; ++i) {
            float4 cc[4];
            #pragma unroll
            for (int r = 0; r < 4; ++r) cc[r] = coef[m0 + i * 16 + hi * 4 + r];
            #pragma unroll
            for (int j = 0; j < 4; ++j) {
                const f32x4 bb = *(const f32x4*)(smem + ((((wc * 8 + i) * 4 + j) * 64) + lane) * 16);
                const int n = n0 + wc * 64 + j * 16 + fr;
                #pragma unroll
                for (int r = 0; r < 4; ++r) {
                    const int m = m0 + i * 16 + hi * 4 + r;
                    const float aa = acc[i][j][r];
                    out[(size_t)m * Nd + n] = cc[r].x + cc[r].y * aa + cc[r].z * bb[r]
                                            + cc[r].w * (aa * bb[r]);
                }
            }
        }
    }
}

// ---------------------------------------------------------------------------
extern "C" void kernel_launch(void* const* d_in, const int* in_sizes, int n_in,
                              void* d_out, int out_size, void* d_ws, size_t ws_size,
                              hipStream_t stream)
{
    const float* prev = (const float*)d_in[0];   // (prev_size, batch)
    const float* WA   = (const float*)d_in[1];   // (size, prev_size)
    const float* WB   = (const float*)d_in[2];   // (size, prev_size)
    const float* TW   = (const float*)d_in[3];   // (16, size)
    float* out = (float*)d_out;                  // (size, batch)

    const int size      = in_sizes[3] / 16;          // 1024
    const int prev_size = in_sizes[1] / size;        // 1024
    const int batch     = in_sizes[0] / prev_size;   // 16384

    char* ws = (char*)d_ws;
    __hip_bfloat16* prevT = (__hip_bfloat16*)ws;     // 32MB
    size_t off = (size_t)batch * prev_size * sizeof(__hip_bfloat16);
    __hip_bfloat16* pA = (__hip_bfloat16*)(ws + off);
    off += (size_t)size * prev_size * sizeof(__hip_bfloat16);
    __hip_bfloat16* pB = (__hip_bfloat16*)(ws + off);
    off += (size_t)size * prev_size * sizeof(__hip_bfloat16);
    float4* coef = (float4*)(ws + off);

    const int nprep = (batch / 64) * (prev_size / 64) + 2 * size + (size + 255) / 256;
    prep_fused<<<dim3(nprep), dim3(256), 0, stream>>>(
        prev, prevT, WA, WB, pA, pB, TW, coef);
    dual_gemm8<<<dim3(batch / 256, size / 128), dim3(512), 0, stream>>>(
        pA, pB, prevT, coef, out);
}